// Round 1
// baseline (78.389 us; speedup 1.0000x reference)
//
#include <hip/hip_runtime.h>
#include <hip/hip_bf16.h>

#define BB 512
#define TT 2048
#define SS 128
#define LL 64
#define PP (TT - LL + 1)   // 1985

typedef __attribute__((ext_vector_type(8))) short  short8;
typedef __attribute__((ext_vector_type(4))) float  float4v;

union U8 { short8 v; unsigned long long u[2]; };

__device__ __forceinline__ unsigned f2bf1(float f) {
  union { float f; unsigned u; } v; v.f = f;
  return (v.u + 0x7FFFu + ((v.u >> 16) & 1u)) >> 16;   // RNE fp32->bf16
}

// One block per sample b. 4 waves x 64 lanes.
// Wave w handles p in {iter*128 + w*32 .. +31}, all 128 shapelets, 16 iters.
__global__ __launch_bounds__(256, 2)
void shapelet_min_dist(const float* __restrict__ x,
                       const float* __restrict__ shg,
                       float* __restrict__ out) {
  __shared__ float xf[2176];                    // fp32 x, zero-padded
  __shared__ unsigned long long xcp[4][532];    // 4 shifted bf16 copies (4 elems/word)
  __shared__ short8 shb8[1024];                 // shapelets bf16 [S][L]
  __shared__ float s2s[SS], ssums[SS];
  __shared__ float c0a[2048], m2a[2048];        // per-window: ||pc||^2 (or INF), 2*mean
  __shared__ float wminl[512];

  const int t = threadIdx.x;
  const int b = blockIdx.x;

  // ---- stage x (fp32) into LDS, zero-pad tail ----
  {
    const float4v* xg4 = (const float4v*)(x + (size_t)b * TT);
    float4v* xf4 = (float4v*)xf;
    xf4[t]       = xg4[t];
    xf4[t + 256] = xg4[t + 256];
    if (t < 32) {
      float4v z = {0.f, 0.f, 0.f, 0.f};
      xf4[512 + t] = z;
    }
  }

  // ---- stage shapelets -> bf16 LDS, compute s2/ssum ----
  {
    const int sidx = t >> 1;
    const int l0 = (t & 1) * 32;
    const float* rowp = shg + sidx * LL + l0;
    unsigned* shbw = (unsigned*)shb8;
    float sum = 0.f, sq = 0.f;
    #pragma unroll
    for (int l = 0; l < 32; l += 2) {
      float a = rowp[l], bv = rowp[l + 1];
      sum += a + bv;
      sq = fmaf(a, a, sq);
      sq = fmaf(bv, bv, sq);
      shbw[(sidx * LL + l0 + l) >> 1] = f2bf1(a) | (f2bf1(bv) << 16);
    }
    sum += __shfl_xor(sum, 1);
    sq  += __shfl_xor(sq, 1);
    if ((t & 1) == 0) { ssums[sidx] = sum; s2s[sidx] = sq; }
  }

  __syncthreads();

  // ---- build 4 element-shifted bf16 copies: xcp[c] word w = bf16(xf[4w+c .. 4w+c+3]) ----
  for (int w = t; w < 532; w += 256) {
    #pragma unroll
    for (int c = 0; c < 4; ++c) {
      int e = 4 * w + c;
      unsigned long long pk =
          (unsigned long long)f2bf1(xf[e]) |
          ((unsigned long long)f2bf1(xf[e + 1]) << 16) |
          ((unsigned long long)f2bf1(xf[e + 2]) << 32) |
          ((unsigned long long)f2bf1(xf[e + 3]) << 48);
      xcp[c][w] = pk;
    }
  }

  // ---- sliding-window stats: c0 = sum(x^2)-sum(x)^2/L, m2 = 2*mean ----
  {
    const int p0 = t * 8;
    const int rt = (57 * t) & 63;           // rotate start to kill stride-8 bank conflicts
    float s = 0.f, qq = 0.f;
    for (int l = 0; l < 64; ++l) {
      float v = xf[p0 + ((l + rt) & 63)];
      s += v; qq = fmaf(v, v, qq);
    }
    {
      int p = p0;
      if (p < PP) { c0a[p] = qq - s * s * (1.f / 64.f); m2a[p] = s * (1.f / 32.f); }
      else        { c0a[p] = INFINITY;                  m2a[p] = 0.f; }
    }
    for (int k = 1; k < 8; ++k) {
      float vo = xf[p0 + k - 1], vi = xf[p0 + k + 63];
      s += vi - vo;
      qq += fmaf(vi, vi, -vo * vo);
      int p = p0 + k;
      if (p < PP) { c0a[p] = qq - s * s * (1.f / 64.f); m2a[p] = s * (1.f / 32.f); }
      else        { c0a[p] = INFINITY;                  m2a[p] = 0.f; }
    }
  }

  __syncthreads();

  // ---- main MFMA loop ----
  const int lane = t & 63, wave = t >> 6;
  const int n = lane & 15, q = lane >> 4;

  // B fragments (shapelets), hoisted for all iters: bf[kb][st]
  short8 bf[2][8];
  #pragma unroll
  for (int st = 0; st < 8; ++st) {
    #pragma unroll
    for (int kb = 0; kb < 2; ++kb)
      bf[kb][st] = shb8[(st * 16 + n) * 8 + kb * 4 + q];
  }

  float ssl[8], s2l[8];
  #pragma unroll
  for (int st = 0; st < 8; ++st) {
    ssl[st] = ssums[st * 16 + n];
    s2l[st] = s2s[st * 16 + n];
  }

  float rmin[8];
  #pragma unroll
  for (int st = 0; st < 8; ++st) rmin[st] = INFINITY;

  const int c = n & 3;
  const int mw = n >> 2;
  const unsigned long long* xc = &xcp[c][0];

  for (int iter = 0; iter < 16; ++iter) {
    const int p0 = iter * 128 + wave * 32;

    float4v acc[2][8] = {};

    #pragma unroll
    for (int mt = 0; mt < 2; ++mt) {
      #pragma unroll
      for (int kb = 0; kb < 2; ++kb) {
        // lane's A elements: x[p0 + mt*16 + kb*32 + (lane&15) + q*8 + j], j=0..7
        int w0 = ((p0 + mt * 16 + kb * 32) >> 2) + mw + (q << 1);
        U8 a;
        a.u[0] = xc[w0];
        a.u[1] = xc[w0 + 1];
        #pragma unroll
        for (int st = 0; st < 8; ++st)
          acc[mt][st] = __builtin_amdgcn_mfma_f32_16x16x32_bf16(
              a.v, bf[kb][st], acc[mt][st], 0, 0, 0);
      }
    }

    // epilogue: d2 = c0[p] + s2[s] + 2*mean[p]*ssum[s] - 2*cross ; running min
    #pragma unroll
    for (int mt = 0; mt < 2; ++mt) {
      int pb = p0 + mt * 16 + q * 4;                 // D row = q*4 + r
      float4v c0v = *(const float4v*)&c0a[pb];
      float4v m2v = *(const float4v*)&m2a[pb];
      #pragma unroll
      for (int st = 0; st < 8; ++st) {
        #pragma unroll
        for (int r = 0; r < 4; ++r) {
          float e  = fmaf(m2v[r], ssl[st], c0v[r] + s2l[st]);
          float d2 = fmaf(-2.f, acc[mt][st][r], e);
          rmin[st] = fminf(rmin[st], d2);
        }
      }
    }
  }

  // ---- reduce: across quads (same s), then across waves via LDS ----
  #pragma unroll
  for (int st = 0; st < 8; ++st) {
    float v = rmin[st];
    v = fminf(v, __shfl_xor(v, 16));
    v = fminf(v, __shfl_xor(v, 32));
    if (q == 0) wminl[wave * 128 + st * 16 + n] = v;
  }
  __syncthreads();

  if (t < SS) {
    float v = fminf(fminf(wminl[t], wminl[128 + t]),
                    fminf(wminl[256 + t], wminl[384 + t]));
    out[(size_t)b * SS + t] = sqrtf(fmaxf(v, 0.f));
  }
}

extern "C" void kernel_launch(void* const* d_in, const int* in_sizes, int n_in,
                              void* d_out, int out_size, void* d_ws, size_t ws_size,
                              hipStream_t stream) {
  const float* x  = (const float*)d_in[0];
  const float* sh = (const float*)d_in[1];
  float* out = (float*)d_out;
  shapelet_min_dist<<<dim3(BB), dim3(256), 0, stream>>>(x, sh, out);
}